// Round 9
// baseline (388.955 us; speedup 1.0000x reference)
//
#include <hip/hip_runtime.h>
#include <math.h>

#define BATCH 8
#define NSEQ  1024
#define DIMC  512
#define HEADS 16
#define HD    32
#define TBLN  3969
#define QROWS (BATCH*HEADS*NSEQ)
#define LOG2E 1.4426950408889634f

typedef __attribute__((ext_vector_type(8))) short bf16x8;
typedef __attribute__((ext_vector_type(4))) float f32x4;

__device__ __forceinline__ unsigned short f2bf(float f) {
  union { float f; unsigned u; } c; c.f = f;
  unsigned x = c.u + 0x7fffu + ((c.u >> 16) & 1u);   // RNE
  return (unsigned short)(x >> 16);
}
__device__ __forceinline__ float bf2f(unsigned short h) {
  union { unsigned u; float f; } c; c.u = ((unsigned)h) << 16; return c.f;
}
__device__ __forceinline__ unsigned cvt_pk_bf16(float lo, float hi) {
  unsigned r;
  asm("v_cvt_pk_bf16_f32 %0, %1, %2" : "=v"(r) : "v"(lo), "v"(hi));
  return r;
}

#define GLD(gsrc, ldst) __builtin_amdgcn_global_load_lds( \
      (const __attribute__((address_space(1))) unsigned int*)(gsrc), \
      (__attribute__((address_space(3))) unsigned int*)(ldst), 16, 0, 0)

// ---------------------------------------------------------------------------
// hi/lo bf16 split of an fp32 array (float4 per thread).
// ---------------------------------------------------------------------------
__global__ __launch_bounds__(256) void split_kernel(
    const float* __restrict__ src, unsigned short* __restrict__ hi,
    unsigned short* __restrict__ lo, int n4)
{
  int gid = blockIdx.x * 256 + threadIdx.x;
  if (gid >= n4) return;
  float4 v = ((const float4*)src)[gid];
  float vv[4] = {v.x, v.y, v.z, v.w};
  unsigned short h[4], l[4];
#pragma unroll
  for (int i = 0; i < 4; ++i) {
    h[i] = f2bf(vv[i]);
    l[i] = f2bf(vv[i] - bf2f(h[i]));
  }
  uint2 hp, lp;
  hp.x = h[0] | ((unsigned)h[1] << 16); hp.y = h[2] | ((unsigned)h[3] << 16);
  lp.x = l[0] | ((unsigned)l[1] << 16); lp.y = l[2] | ((unsigned)l[3] << 16);
  ((uint2*)hi)[gid] = hp;
  ((uint2*)lo)[gid] = lp;
}

// ---------------------------------------------------------------------------
// Split-bf16 MFMA GEMM (unchanged; conflicts measured 0).
// ---------------------------------------------------------------------------
template<int EPI>
__global__ __launch_bounds__(256) void gemm_split_kernel(
    const unsigned short* __restrict__ Ah, const unsigned short* __restrict__ Al,
    const unsigned short* __restrict__ Wh, const unsigned short* __restrict__ Wl,
    const float* __restrict__ bias,
    float* __restrict__ o0p, float* __restrict__ o1p, float* __restrict__ o2p)
{
  const int K = DIMC;
  __shared__ __align__(16) unsigned short lds[4 * 4096];
  unsigned short* ldsAh = lds;
  unsigned short* ldsAl = lds + 4096;
  unsigned short* ldsBh = lds + 8192;
  unsigned short* ldsBl = lds + 12288;
  const int tid = threadIdx.x;
  const int wave = tid >> 6, lane = tid & 63;
  const int l16 = lane & 15, hi4 = lane >> 4;
  const int rowBase = blockIdx.y * 128, colBase = blockIdx.x * 128;
  const int warpRow = (wave >> 1) * 64, warpCol = (wave & 1) * 64;

  const int o0 = wave * 2048 + lane * 16;
  const int o1 = o0 + 1024;
  const int row0 = o0 >> 6, s0 = (o0 >> 4) & 3;
  const int row1 = o1 >> 6, s1 = (o1 >> 4) & 3;
  const int g0 = row0 * K + ((s0 ^ ((row0 >> 1) & 3)) << 3);
  const int g1 = row1 * K + ((s1 ^ ((row1 >> 1) & 3)) << 3);

  const unsigned short* A0h = Ah + (size_t)rowBase * K;
  const unsigned short* A0l = Al + (size_t)rowBase * K;
  const unsigned short* W0h = Wh + (size_t)colBase * K;
  const unsigned short* W0l = Wl + (size_t)colBase * K;

  f32x4 acc[4][4] = {};

  float biasv[4];
#pragma unroll
  for (int fj = 0; fj < 4; ++fj)
    biasv[fj] = bias[colBase + warpCol + fj * 16 + l16];

  int ra[4], rbq[4];
#pragma unroll
  for (int f = 0; f < 4; ++f) {
    int rowA = warpRow + f * 16 + l16;
    ra[f] = rowA * 64 + ((hi4 ^ ((rowA >> 1) & 3)) << 4);
    int rowB = warpCol + f * 16 + l16;
    rbq[f] = rowB * 64 + ((hi4 ^ ((rowB >> 1) & 3)) << 4);
  }

  for (int k0 = 0; k0 < K; k0 += 32) {
    __syncthreads();
    GLD(A0h + k0 + g0, (char*)ldsAh + o0);
    GLD(A0h + k0 + g1, (char*)ldsAh + o1);
    GLD(A0l + k0 + g0, (char*)ldsAl + o0);
    GLD(A0l + k0 + g1, (char*)ldsAl + o1);
    GLD(W0h + k0 + g0, (char*)ldsBh + o0);
    GLD(W0h + k0 + g1, (char*)ldsBh + o1);
    GLD(W0l + k0 + g0, (char*)ldsBl + o0);
    GLD(W0l + k0 + g1, (char*)ldsBl + o1);
    __syncthreads();

    bf16x8 a_h[4], a_l[4], b_h[4], b_l[4];
#pragma unroll
    for (int f = 0; f < 4; ++f) {
      a_h[f] = *(const bf16x8*)((const char*)ldsAh + ra[f]);
      a_l[f] = *(const bf16x8*)((const char*)ldsAl + ra[f]);
      b_h[f] = *(const bf16x8*)((const char*)ldsBh + rbq[f]);
      b_l[f] = *(const bf16x8*)((const char*)ldsBl + rbq[f]);
    }
#pragma unroll
    for (int fi = 0; fi < 4; ++fi)
#pragma unroll
      for (int fj = 0; fj < 4; ++fj) {
        acc[fi][fj] = __builtin_amdgcn_mfma_f32_16x16x32_bf16(a_l[fi], b_h[fj], acc[fi][fj], 0, 0, 0);
        acc[fi][fj] = __builtin_amdgcn_mfma_f32_16x16x32_bf16(a_h[fi], b_l[fj], acc[fi][fj], 0, 0, 0);
        acc[fi][fj] = __builtin_amdgcn_mfma_f32_16x16x32_bf16(a_h[fi], b_h[fj], acc[fi][fj], 0, 0, 0);
      }
  }

#pragma unroll
  for (int fi = 0; fi < 4; ++fi)
#pragma unroll
    for (int fj = 0; fj < 4; ++fj)
#pragma unroll
      for (int r = 0; r < 4; ++r) {
        int m = rowBase + warpRow + fi * 16 + hi4 * 4 + r;
        int c = colBase + warpCol + fj * 16 + l16;
        float val = acc[fi][fj][r] + biasv[fj];
        if (EPI == 0) {
          int b = m >> 10, n = m & 1023;
          int which = c >> 9, rem = c & 511;
          int hh = rem >> 5, d = rem & 31;
          float* dst = (which == 0) ? o0p : (which == 1) ? o1p : o2p;
          dst[(((size_t)b * HEADS + hh) * NSEQ + n) * HD + d] = val;
        } else {
          o0p[(size_t)m * DIMC + c] = val;
        }
      }
}

// ---------------------------------------------------------------------------
// CPB MLP (unchanged) -> tT [16][TBLN] f32
// ---------------------------------------------------------------------------
__global__ __launch_bounds__(256) void cpb_kernel(
    const float* __restrict__ table, const float* __restrict__ fc1w,
    const float* __restrict__ fc1b, const float* __restrict__ fc2w,
    const float* __restrict__ fc2b, float* __restrict__ tT)
{
  const int row = blockIdx.x;
  const float c0 = table[row*2], c1 = table[row*2+1];
  __shared__ float hid[512];
  __shared__ float red[256];
  const int tid = threadIdx.x;
  for (int j = tid; j < 512; j += 256)
    hid[j] = fmaxf(fmaf(c0, fc1w[j*2], fmaf(c1, fc1w[j*2+1], fc1b[j])), 0.f);
  __syncthreads();
  const int h = tid & 15, part = tid >> 4;
  float s = 0.f;
#pragma unroll
  for (int jj = 0; jj < 32; ++jj) {
    int j = part*32 + jj;
    s = fmaf(hid[j], fc2w[h*512 + j], s);
  }
  red[tid] = s;
  __syncthreads();
  if (tid < 16) {
    float t = fc2b[tid];
#pragma unroll
    for (int p = 0; p < 16; ++p) t += red[tid + p*16];
    tT[(size_t)tid * TBLN + row] = t;
  }
}

// ---------------------------------------------------------------------------
// rb materialization, PRE-SCALED by log2e (unchanged).
// ---------------------------------------------------------------------------
__global__ __launch_bounds__(256) void rb_gather_kernel(
    const float* __restrict__ tT, const int* __restrict__ rpi,
    unsigned short* __restrict__ rb)
{
  int gid = blockIdx.x * 256 + threadIdx.x;
  int idx = rpi[gid];
#pragma unroll
  for (int h = 0; h < 16; ++h)
    rb[(size_t)h * NSEQ * NSEQ + gid] = f2bf(tT[h * TBLN + idx] * LOG2E);
}

// ---------------------------------------------------------------------------
// Per-(h,q) row max of rb (unchanged).
// ---------------------------------------------------------------------------
__global__ __launch_bounds__(256) void rowmax_kernel(
    const unsigned short* __restrict__ rb, float* __restrict__ rbmax)
{
  const int row = blockIdx.x * 4 + (threadIdx.x >> 6);
  const int lane = threadIdx.x & 63;
  const unsigned short* src = rb + (size_t)row * NSEQ + lane * 16;
  bf16x8 a = *(const bf16x8*)src;
  bf16x8 b = *(const bf16x8*)(src + 8);
  float m = -1e30f;
#pragma unroll
  for (int j = 0; j < 8; ++j) {
    m = fmaxf(m, bf2f((unsigned short)a[j]));
    m = fmaxf(m, bf2f((unsigned short)b[j]));
  }
#pragma unroll
  for (int s = 32; s >= 1; s >>= 1) m = fmaxf(m, __shfl_xor(m, s));
  if (lane == 0) rbmax[row] = m;
}

// ---------------------------------------------------------------------------
// Normalize q,k, emit hi/lo bf16 splits + qmag (unchanged).
// ---------------------------------------------------------------------------
__global__ __launch_bounds__(256) void normsplit_kernel(
    const float* __restrict__ qb, const float* __restrict__ kb,
    const float* __restrict__ temperature, const float* __restrict__ qe,
    const float* __restrict__ sls,
    unsigned short* __restrict__ qh, unsigned short* __restrict__ ql,
    unsigned short* __restrict__ kh, unsigned short* __restrict__ kl,
    float* __restrict__ qmag)
{
  const int gid = blockIdx.x * 256 + threadIdx.x;
  const int lane = gid & 31;
  const int row = gid >> 5;
  const bool isQ = row < QROWS;
  const float* src = isQ ? qb : kb;
  const int r = isQ ? row : row - QROWS;
  float x = src[(size_t)r * HD + lane];
  float ss = x * x;
#pragma unroll
  for (int m = 16; m >= 1; m >>= 1) ss += __shfl_xor(ss, m);
  float y = x / fmaxf(sqrtf(ss), 1e-12f);
  if (isQ) {
    const int h = (r >> 10) & (HEADS - 1);
    float scale = log1pf(__expf(temperature[h])) * sls[0];
    y = (y + qe[h * HD + lane]) * scale;
    float s2 = y * y;
#pragma unroll
    for (int m = 16; m >= 1; m >>= 1) s2 += __shfl_xor(s2, m);
    if (lane == 0) qmag[r] = sqrtf(s2);
  }
  unsigned short hi = f2bf(y);
  unsigned short lo = f2bf(y - bf2f(hi));
  size_t idx = (size_t)r * HD + lane;
  if (isQ) { qh[idx] = hi; ql[idx] = lo; }
  else     { kh[idx] = hi; kl[idx] = lo; }
}

// ---------------------------------------------------------------------------
// V transpose (unchanged): vb f32 [bh][n][32] -> vt bf16 [bh][32][n].
// ---------------------------------------------------------------------------
__global__ __launch_bounds__(256) void vt_kernel(
    const float* __restrict__ vb, unsigned short* __restrict__ vt)
{
  __shared__ float tile[32][257];
  const int bh = blockIdx.x, ch = blockIdx.y;
  const int t = threadIdx.x;
  const float* src = vb + ((size_t)bh * NSEQ + ch * 256) * HD;
#pragma unroll
  for (int i = 0; i < 32; ++i) {
    int idx = i * 256 + t;
    tile[idx & 31][idx >> 5] = src[idx];
  }
  __syncthreads();
  unsigned short* dst = vt + (size_t)bh * HD * NSEQ + ch * 256;
#pragma unroll
  for (int i = 0; i < 32; ++i) {
    int idx = i * 256 + t;
    int d = idx >> 8, nl = idx & 255;
    dst[(size_t)d * NSEQ + nl] = f2bf(tile[d][nl]);
  }
}

// ---------------------------------------------------------------------------
// MFMA flash attention, static-bound softmax (proven math) + DEEP prefetch:
// rb is a 32MB read-once stream -> every rb load is a ~900-cycle cold miss;
// depth-1 prefetch (round 8) could not cover it (dur unchanged 106->102->102).
// Now: rb prefetched 4 tiles ahead (4 static register pairs rotated by an
// unroll-4 loop), K/V double-buffered (L2-warm, ~200-300cy). All names
// static (no runtime-indexed arrays -> no scratch). launch_bounds(256,3).
// ---------------------------------------------------------------------------
__global__ __launch_bounds__(256, 3) void attn_mfma_kernel(
    const unsigned short* __restrict__ qh, const unsigned short* __restrict__ ql,
    const unsigned short* __restrict__ kh, const unsigned short* __restrict__ kl,
    const unsigned short* __restrict__ vt, const unsigned short* __restrict__ rb,
    const float* __restrict__ qmag, const float* __restrict__ rbmax,
    unsigned short* __restrict__ aoh, unsigned short* __restrict__ aol)
{
  const int bh = blockIdx.x;
  const int h = bh & (HEADS - 1), b = bh >> 4;
  const int wave = threadIdx.x >> 6;
  const int lane = threadIdx.x & 63;
  const int l16 = lane & 15, hi4 = lane >> 4;
  const int qbase = blockIdx.y * 128 + wave * 32;

  bf16x8 qhf[2], qlf[2];
  float Ms[2];
#pragma unroll
  for (int g = 0; g < 2; ++g) {
    const int qrow = qbase + g * 16 + l16;
    size_t ro = ((size_t)bh * NSEQ + qrow) * HD + hi4 * 8;
    qhf[g] = *(const bf16x8*)(qh + ro);
    qlf[g] = *(const bf16x8*)(ql + ro);
    Ms[g] = qmag[(size_t)bh * NSEQ + qrow] * (1.01f * LOG2E)
            + rbmax[h * NSEQ + qrow] + 0.2f;
  }

  bf16x8 ones;
#pragma unroll
  for (int j = 0; j < 8; ++j) ones[j] = (short)0x3f80;

  f32x4 accV[2][2] = {};
  f32x4 accL[2] = {};

  const int krow_p = 8 * (l16 >> 2) + (l16 & 3);   // permuted key row
  const unsigned short* khg  = kh + ((size_t)bh * NSEQ + krow_p) * HD + hi4 * 8;
  const unsigned short* klg  = kl + ((size_t)bh * NSEQ + krow_p) * HD + hi4 * 8;
  const unsigned short* vtg  = vt + ((size_t)bh * HD + l16) * NSEQ + hi4 * 8;
  const unsigned short* rbg0 = rb + ((size_t)h * NSEQ + qbase + l16) * NSEQ + hi4 * 8;
  const unsigned short* rbg1 = rbg0 + (size_t)16 * NSEQ;

// K/V fragment set S for tile KT. Overreads at KT in {32} land in adjacent
// ws buffers (allocated), values never used.
#define LOADKV(S, KT) do { \
    const size_t ko_ = (size_t)(KT) * 32 * HD; \
    const size_t vo_ = (size_t)(KT) * 32; \
    kh0##S = *(const bf16x8*)(khg + ko_); \
    kh1##S = *(const bf16x8*)(khg + ko_ + 4 * HD); \
    kl0##S = *(const bf16x8*)(klg + ko_); \
    kl1##S = *(const bf16x8*)(klg + ko_ + 4 * HD); \
    vt0##S = *(const bf16x8*)(vtg + vo_); \
    vt1##S = *(const bf16x8*)(vtg + vo_ + (size_t)16 * NSEQ); \
  } while (0)

// rb pair for tile KT (cold stream; up to KT=35 overreads stay in rb buffer).
#define LOADRB(Ra, Rb, KT) do { \
    Ra = *(const bf16x8*)(rbg0 + (size_t)(KT) * 32); \
    Rb = *(const bf16x8*)(rbg1 + (size_t)(KT) * 32); \
  } while (0)

#define COMPUTE(S, Ra, Rb) do { \
    _Pragma("unroll") \
    for (int g = 0; g < 2; ++g) { \
      bf16x8 b8v = g ? (Rb) : (Ra); \
      f32x4 D0 = {0.f, 0.f, 0.f, 0.f}; \
      f32x4 D1 = {0.f, 0.f, 0.f, 0.f}; \
      __builtin_amdgcn_s_setprio(1); \
      D0 = __builtin_amdgcn_mfma_f32_16x16x32_bf16(kh0##S, qhf[g], D0, 0, 0, 0); \
      D0 = __builtin_amdgcn_mfma_f32_16x16x32_bf16(kh0##S, qlf[g], D0, 0, 0, 0); \
      D0 = __builtin_amdgcn_mfma_f32_16x16x32_bf16(kl0##S, qhf[g], D0, 0, 0, 0); \
      D1 = __builtin_amdgcn_mfma_f32_16x16x32_bf16(kh1##S, qhf[g], D1, 0, 0, 0); \
      D1 = __builtin_amdgcn_mfma_f32_16x16x32_bf16(kh1##S, qlf[g], D1, 0, 0, 0); \
      D1 = __builtin_amdgcn_mfma_f32_16x16x32_bf16(kl1##S, qhf[g], D1, 0, 0, 0); \
      __builtin_amdgcn_s_setprio(0); \
      float p0[4], p1[4]; \
      _Pragma("unroll") \
      for (int r = 0; r < 4; ++r) { \
        float a0 = fmaf(D0[r], LOG2E, bf2f((unsigned short)b8v[r]))     - Ms[g]; \
        float a1 = fmaf(D1[r], LOG2E, bf2f((unsigned short)b8v[4 + r])) - Ms[g]; \
        p0[r] = __builtin_amdgcn_exp2f(a0); \
        p1[r] = __builtin_amdgcn_exp2f(a1); \
      } \
      union { bf16x8 v; unsigned u[4]; } pa; \
      pa.u[0] = cvt_pk_bf16(p0[0], p0[1]); \
      pa.u[1] = cvt_pk_bf16(p0[2], p0[3]); \
      pa.u[2] = cvt_pk_bf16(p1[0], p1[1]); \
      pa.u[3] = cvt_pk_bf16(p1[2], p1[3]); \
      __builtin_amdgcn_s_setprio(1); \
      accV[g][0] = __builtin_amdgcn_mfma_f32_16x16x32_bf16(pa.v, vt0##S, accV[g][0], 0, 0, 0); \
      accV[g][1] = __builtin_amdgcn_mfma_f32_16x16x32_bf16(pa.v, vt1##S, accV[g][1], 0, 0, 0); \
      accL[g]    = __builtin_amdgcn_mfma_f32_16x16x32_bf16(pa.v, ones, accL[g], 0, 0, 0); \
      __builtin_amdgcn_s_setprio(0); \
    } \
  } while (0)

  bf16x8 kh0A, kh1A, kl0A, kl1A, vt0A, vt1A;
  bf16x8 kh0B, kh1B, kl0B, kl1B, vt0B, vt1B;
  bf16x8 r0a, r0b, r1a, r1b, r2a, r2b, r3a, r3b;

  // prologue: rb 4 tiles deep, K/V tile 0
  LOADRB(r0a, r0b, 0);
  LOADRB(r1a, r1b, 1);
  LOADRB(r2a, r2b, 2);
  LOADRB(r3a, r3b, 3);
  LOADKV(A, 0);

  for (int kt = 0; kt < 32; kt += 4) {
    LOADKV(B, kt + 1);
    COMPUTE(A, r0a, r0b);          // tile kt
    LOADRB(r0a, r0b, kt + 4);      // refill rb slot 0 (4 ahead)
    LOADKV(A, kt + 2);
    COMPUTE(B, r1a, r1b);          // tile kt+1
    LOADRB(r1a, r1b, kt + 5);
    LOADKV(B, kt + 3);
    COMPUTE(A, r2a, r2b);          // tile kt+2
    LOADRB(r2a, r2b, kt + 6);
    LOADKV(A, kt + 4);             // kt=28 -> tile 32 overread (safe)
    COMPUTE(B, r3a, r3b);          // tile kt+3
    LOADRB(r3a, r3b, kt + 7);      // up to tile 35 overread (safe, in-buffer)
  }
#undef LOADKV
#undef LOADRB
#undef COMPUTE

#pragma unroll
  for (int g = 0; g < 2; ++g)
#pragma unroll
    for (int r = 0; r < 4; ++r) {
      float inv = 1.f / accL[g][r];
#pragma unroll
      for (int df = 0; df < 2; ++df) {
        size_t idx = ((size_t)b * NSEQ + qbase + g * 16 + hi4 * 4 + r) * DIMC
                     + h * HD + df * 16 + l16;
        float val = accV[g][df][r] * inv;
        unsigned short hh = f2bf(val);
        aoh[idx] = hh;
        aol[idx] = f2bf(val - bf2f(hh));
      }
    }
}

// ---------------------------------------------------------------------------
extern "C" void kernel_launch(void* const* d_in, const int* in_sizes, int n_in,
                              void* d_out, int out_size, void* d_ws, size_t ws_size,
                              hipStream_t stream)
{
  (void)in_sizes; (void)n_in; (void)out_size; (void)ws_size;
  const float* x      = (const float*)d_in[0];
  const float* qkv_w  = (const float*)d_in[1];
  const float* qkv_b  = (const float*)d_in[2];
  const float* proj_w = (const float*)d_in[3];
  const float* proj_b = (const float*)d_in[4];
  const float* temp   = (const float*)d_in[5];
  const float* qe     = (const float*)d_in[6];
  const float* fc1w   = (const float*)d_in[7];
  const float* fc1b   = (const float*)d_in[8];
  const float* fc2w   = (const float*)d_in[9];
  const float* fc2b   = (const float*)d_in[10];
  const float* tbl    = (const float*)d_in[11];
  const int*   rpi    = (const int*)d_in[12];
  const float* sls    = (const float*)d_in[13];
  // H=W=32 == trained resolution: both bilinear resizes are identity;
  // bias[h,n,m] = t[rpi[n*1024+m], h].

  char* ws = (char*)d_ws;
  const size_t perT = (size_t)BATCH * HEADS * NSEQ * HD;    // 4,194,304
  float* qb = (float*)ws;
  float* kb = qb + perT;
  float* vb = kb + perT;
  float* tT = vb + perT;                                    // 65536 f32 slot
  unsigned short* qh = (unsigned short*)(tT + 65536);
  unsigned short* ql = qh + perT;
  unsigned short* kh = ql + perT;
  unsigned short* kl = kh + perT;
  unsigned short* vt = kl + perT;
  unsigned short* xh = vt + perT;
  unsigned short* xl = xh + perT;
  unsigned short* pwh = xl + perT;                          // 262144
  unsigned short* pwl = pwh + 262144;
  float* rbmax = (float*)(pwl + 262144);                    // 16384 f32
  float* qmag  = rbmax + 16384;                             // QROWS f32
  // aliases (stream-ordered lifetimes):
  unsigned short* qwh = qh;              // dead before normsplit writes qh
  unsigned short* qwl = qh + 786432;
  unsigned short* rb  = (unsigned short*)qb;  // qb/kb dead after normsplit
  unsigned short* aoh = xh;              // xh/xl dead after gemm_qkv
  unsigned short* aol = xl;

  split_kernel<<<dim3(4096), 256, 0, stream>>>(x, xh, xl, 1048576);
  split_kernel<<<dim3(768),  256, 0, stream>>>(qkv_w, qwh, qwl, 196608);
  split_kernel<<<dim3(256),  256, 0, stream>>>(proj_w, pwh, pwl, 65536);
  gemm_split_kernel<0><<<dim3(12, 64), 256, 0, stream>>>(
      xh, xl, qwh, qwl, qkv_b, qb, kb, vb);
  cpb_kernel<<<dim3(TBLN), 256, 0, stream>>>(tbl, fc1w, fc1b, fc2w, fc2b, tT);
  normsplit_kernel<<<dim3((2*QROWS*32)/256), 256, 0, stream>>>(
      qb, kb, temp, qe, sls, qh, ql, kh, kl, qmag);
  vt_kernel<<<dim3(BATCH*HEADS, NSEQ/256), 256, 0, stream>>>(vb, vt);
  rb_gather_kernel<<<dim3((NSEQ*NSEQ)/256), 256, 0, stream>>>(tT, rpi, rb);
  rowmax_kernel<<<dim3(HEADS*NSEQ/4), 256, 0, stream>>>(rb, rbmax);
  attn_mfma_kernel<<<dim3(BATCH*HEADS, NSEQ/128), 256, 0, stream>>>(
      qh, ql, kh, kl, vt, rb, qmag, rbmax, aoh, aol);
  gemm_split_kernel<1><<<dim3(4, 64), 256, 0, stream>>>(
      aoh, aol, pwh, pwl, proj_b, (float*)d_out, nullptr, nullptr);
}

// Round 10
// 353.665 us; speedup vs baseline: 1.0998x; 1.0998x over previous
//
#include <hip/hip_runtime.h>
#include <math.h>

#define BATCH 8
#define NSEQ  1024
#define DIMC  512
#define HEADS 16
#define HD    32
#define TBLN  3969
#define QROWS (BATCH*HEADS*NSEQ)
#define LOG2E 1.4426950408889634f

typedef __attribute__((ext_vector_type(8))) short bf16x8;
typedef __attribute__((ext_vector_type(4))) float f32x4;

__device__ __forceinline__ unsigned short f2bf(float f) {
  union { float f; unsigned u; } c; c.f = f;
  unsigned x = c.u + 0x7fffu + ((c.u >> 16) & 1u);   // RNE
  return (unsigned short)(x >> 16);
}
__device__ __forceinline__ float bf2f(unsigned short h) {
  union { unsigned u; float f; } c; c.u = ((unsigned)h) << 16; return c.f;
}
__device__ __forceinline__ unsigned cvt_pk_bf16(float lo, float hi) {
  unsigned r;
  asm("v_cvt_pk_bf16_f32 %0, %1, %2" : "=v"(r) : "v"(lo), "v"(hi));
  return r;
}

#define GLD(gsrc, ldst) __builtin_amdgcn_global_load_lds( \
      (const __attribute__((address_space(1))) unsigned int*)(gsrc), \
      (__attribute__((address_space(3))) unsigned int*)(ldst), 16, 0, 0)

// ---------------------------------------------------------------------------
// hi/lo bf16 split of an fp32 array (float4 per thread).
// ---------------------------------------------------------------------------
__global__ __launch_bounds__(256) void split_kernel(
    const float* __restrict__ src, unsigned short* __restrict__ hi,
    unsigned short* __restrict__ lo, int n4)
{
  int gid = blockIdx.x * 256 + threadIdx.x;
  if (gid >= n4) return;
  float4 v = ((const float4*)src)[gid];
  float vv[4] = {v.x, v.y, v.z, v.w};
  unsigned short h[4], l[4];
#pragma unroll
  for (int i = 0; i < 4; ++i) {
    h[i] = f2bf(vv[i]);
    l[i] = f2bf(vv[i] - bf2f(h[i]));
  }
  uint2 hp, lp;
  hp.x = h[0] | ((unsigned)h[1] << 16); hp.y = h[2] | ((unsigned)h[3] << 16);
  lp.x = l[0] | ((unsigned)l[1] << 16); lp.y = l[2] | ((unsigned)l[3] << 16);
  ((uint2*)hi)[gid] = hp;
  ((uint2*)lo)[gid] = lp;
}

// ---------------------------------------------------------------------------
// Split-bf16 MFMA GEMM (unchanged; conflicts measured 0).
// ---------------------------------------------------------------------------
template<int EPI>
__global__ __launch_bounds__(256) void gemm_split_kernel(
    const unsigned short* __restrict__ Ah, const unsigned short* __restrict__ Al,
    const unsigned short* __restrict__ Wh, const unsigned short* __restrict__ Wl,
    const float* __restrict__ bias,
    float* __restrict__ o0p, float* __restrict__ o1p, float* __restrict__ o2p)
{
  const int K = DIMC;
  __shared__ __align__(16) unsigned short lds[4 * 4096];
  unsigned short* ldsAh = lds;
  unsigned short* ldsAl = lds + 4096;
  unsigned short* ldsBh = lds + 8192;
  unsigned short* ldsBl = lds + 12288;
  const int tid = threadIdx.x;
  const int wave = tid >> 6, lane = tid & 63;
  const int l16 = lane & 15, hi4 = lane >> 4;
  const int rowBase = blockIdx.y * 128, colBase = blockIdx.x * 128;
  const int warpRow = (wave >> 1) * 64, warpCol = (wave & 1) * 64;

  const int o0 = wave * 2048 + lane * 16;
  const int o1 = o0 + 1024;
  const int row0 = o0 >> 6, s0 = (o0 >> 4) & 3;
  const int row1 = o1 >> 6, s1 = (o1 >> 4) & 3;
  const int g0 = row0 * K + ((s0 ^ ((row0 >> 1) & 3)) << 3);
  const int g1 = row1 * K + ((s1 ^ ((row1 >> 1) & 3)) << 3);

  const unsigned short* A0h = Ah + (size_t)rowBase * K;
  const unsigned short* A0l = Al + (size_t)rowBase * K;
  const unsigned short* W0h = Wh + (size_t)colBase * K;
  const unsigned short* W0l = Wl + (size_t)colBase * K;

  f32x4 acc[4][4] = {};

  float biasv[4];
#pragma unroll
  for (int fj = 0; fj < 4; ++fj)
    biasv[fj] = bias[colBase + warpCol + fj * 16 + l16];

  int ra[4], rbq[4];
#pragma unroll
  for (int f = 0; f < 4; ++f) {
    int rowA = warpRow + f * 16 + l16;
    ra[f] = rowA * 64 + ((hi4 ^ ((rowA >> 1) & 3)) << 4);
    int rowB = warpCol + f * 16 + l16;
    rbq[f] = rowB * 64 + ((hi4 ^ ((rowB >> 1) & 3)) << 4);
  }

  for (int k0 = 0; k0 < K; k0 += 32) {
    __syncthreads();
    GLD(A0h + k0 + g0, (char*)ldsAh + o0);
    GLD(A0h + k0 + g1, (char*)ldsAh + o1);
    GLD(A0l + k0 + g0, (char*)ldsAl + o0);
    GLD(A0l + k0 + g1, (char*)ldsAl + o1);
    GLD(W0h + k0 + g0, (char*)ldsBh + o0);
    GLD(W0h + k0 + g1, (char*)ldsBh + o1);
    GLD(W0l + k0 + g0, (char*)ldsBl + o0);
    GLD(W0l + k0 + g1, (char*)ldsBl + o1);
    __syncthreads();

    bf16x8 a_h[4], a_l[4], b_h[4], b_l[4];
#pragma unroll
    for (int f = 0; f < 4; ++f) {
      a_h[f] = *(const bf16x8*)((const char*)ldsAh + ra[f]);
      a_l[f] = *(const bf16x8*)((const char*)ldsAl + ra[f]);
      b_h[f] = *(const bf16x8*)((const char*)ldsBh + rbq[f]);
      b_l[f] = *(const bf16x8*)((const char*)ldsBl + rbq[f]);
    }
#pragma unroll
    for (int fi = 0; fi < 4; ++fi)
#pragma unroll
      for (int fj = 0; fj < 4; ++fj) {
        acc[fi][fj] = __builtin_amdgcn_mfma_f32_16x16x32_bf16(a_l[fi], b_h[fj], acc[fi][fj], 0, 0, 0);
        acc[fi][fj] = __builtin_amdgcn_mfma_f32_16x16x32_bf16(a_h[fi], b_l[fj], acc[fi][fj], 0, 0, 0);
        acc[fi][fj] = __builtin_amdgcn_mfma_f32_16x16x32_bf16(a_h[fi], b_h[fj], acc[fi][fj], 0, 0, 0);
      }
  }

#pragma unroll
  for (int fi = 0; fi < 4; ++fi)
#pragma unroll
    for (int fj = 0; fj < 4; ++fj)
#pragma unroll
      for (int r = 0; r < 4; ++r) {
        int m = rowBase + warpRow + fi * 16 + hi4 * 4 + r;
        int c = colBase + warpCol + fj * 16 + l16;
        float val = acc[fi][fj][r] + biasv[fj];
        if (EPI == 0) {
          int b = m >> 10, n = m & 1023;
          int which = c >> 9, rem = c & 511;
          int hh = rem >> 5, d = rem & 31;
          float* dst = (which == 0) ? o0p : (which == 1) ? o1p : o2p;
          dst[(((size_t)b * HEADS + hh) * NSEQ + n) * HD + d] = val;
        } else {
          o0p[(size_t)m * DIMC + c] = val;
        }
      }
}

// ---------------------------------------------------------------------------
// CPB MLP (unchanged) -> tT [16][TBLN] f32
// ---------------------------------------------------------------------------
__global__ __launch_bounds__(256) void cpb_kernel(
    const float* __restrict__ table, const float* __restrict__ fc1w,
    const float* __restrict__ fc1b, const float* __restrict__ fc2w,
    const float* __restrict__ fc2b, float* __restrict__ tT)
{
  const int row = blockIdx.x;
  const float c0 = table[row*2], c1 = table[row*2+1];
  __shared__ float hid[512];
  __shared__ float red[256];
  const int tid = threadIdx.x;
  for (int j = tid; j < 512; j += 256)
    hid[j] = fmaxf(fmaf(c0, fc1w[j*2], fmaf(c1, fc1w[j*2+1], fc1b[j])), 0.f);
  __syncthreads();
  const int h = tid & 15, part = tid >> 4;
  float s = 0.f;
#pragma unroll
  for (int jj = 0; jj < 32; ++jj) {
    int j = part*32 + jj;
    s = fmaf(hid[j], fc2w[h*512 + j], s);
  }
  red[tid] = s;
  __syncthreads();
  if (tid < 16) {
    float t = fc2b[tid];
#pragma unroll
    for (int p = 0; p < 16; ++p) t += red[tid + p*16];
    tT[(size_t)tid * TBLN + row] = t;
  }
}

// ---------------------------------------------------------------------------
// rb materialization into TILED fragment layout, pre-scaled by log2e:
// rbT[((h*64 + n>>4)*32 + kt)*512 + ((n&15) + 16*((m>>3)&3))*8 + (m&7)]
//   = bf16(tT[h][rpi[n*1024+m]] * LOG2E),  kt = m>>5.
// Thread handles 8 consecutive m -> one contiguous bf16x8 store per h.
// In attn, a wave's rb tile load is 1KB fully contiguous.
// ---------------------------------------------------------------------------
__global__ __launch_bounds__(256) void rb_gather_kernel(
    const float* __restrict__ tT, const int* __restrict__ rpi,
    unsigned short* __restrict__ rbT)
{
  int gid = blockIdx.x * 256 + threadIdx.x;   // over N*(N/8)
  int n = gid >> 7, m8 = gid & 127;
  int idx[8];
#pragma unroll
  for (int j = 0; j < 8; ++j) idx[j] = rpi[(size_t)n * NSEQ + m8 * 8 + j];
  const int kt = m8 >> 2, hi4v = m8 & 3;
  const size_t base = (((size_t)0 * 64 + (n >> 4)) * 32 + kt) * 512
                      + ((n & 15) + 16 * hi4v) * 8;
#pragma unroll
  for (int h = 0; h < 16; ++h) {
    bf16x8 v;
#pragma unroll
    for (int j = 0; j < 8; ++j)
      v[j] = (short)f2bf(tT[h * TBLN + idx[j]] * LOG2E);
    *(bf16x8*)(rbT + base + (size_t)h * 64 * 32 * 512) = v;
  }
}

// ---------------------------------------------------------------------------
// Per-(h,q) row max over tiled rbT: rbmax[h*1024+n] = max_m.
// One wave per row; lane l: kt=l>>1, covers hi4v in {2*(l&1), 2*(l&1)+1}.
// ---------------------------------------------------------------------------
__global__ __launch_bounds__(256) void rowmax_kernel(
    const unsigned short* __restrict__ rbT, float* __restrict__ rbmax)
{
  const int row = blockIdx.x * 4 + (threadIdx.x >> 6);
  const int lane = threadIdx.x & 63;
  const int h = row >> 10, n = row & 1023;
  const int kt = lane >> 1, half = lane & 1;
  const size_t base = (((size_t)h * 64 + (n >> 4)) * 32 + kt) * 512;
  bf16x8 a = *(const bf16x8*)(rbT + base + ((n & 15) + 16 * (2 * half)) * 8);
  bf16x8 b = *(const bf16x8*)(rbT + base + ((n & 15) + 16 * (2 * half + 1)) * 8);
  float m = -1e30f;
#pragma unroll
  for (int j = 0; j < 8; ++j) {
    m = fmaxf(m, bf2f((unsigned short)a[j]));
    m = fmaxf(m, bf2f((unsigned short)b[j]));
  }
#pragma unroll
  for (int s = 32; s >= 1; s >>= 1) m = fmaxf(m, __shfl_xor(m, s));
  if (lane == 0) rbmax[row] = m;
}

// ---------------------------------------------------------------------------
// Normalize q,k, emit hi/lo bf16 splits + qmag. Q stays row-major; K is
// written in TILED fragment layout so attn K-loads are 1KB contiguous:
// for key row n, dim d: kt=n>>5, kr=n&31, s=bit2(kr), l16=4*(kr>>3)+(kr&3),
// addr = ((bh*32+kt)*2+s)*512 + (l16 + 16*(d>>3))*8 + (d&7).
// (Matches the validated krow_p = 8*(l16>>2)+(l16&3) (+4 for s=1) read map.)
// ---------------------------------------------------------------------------
__global__ __launch_bounds__(256) void normsplit_kernel(
    const float* __restrict__ qb, const float* __restrict__ kb,
    const float* __restrict__ temperature, const float* __restrict__ qe,
    const float* __restrict__ sls,
    unsigned short* __restrict__ qh, unsigned short* __restrict__ ql,
    unsigned short* __restrict__ khT, unsigned short* __restrict__ klT,
    float* __restrict__ qmag)
{
  const int gid = blockIdx.x * 256 + threadIdx.x;
  const int lane = gid & 31;             // d
  const int row = gid >> 5;
  const bool isQ = row < QROWS;
  const float* src = isQ ? qb : kb;
  const int r = isQ ? row : row - QROWS;
  float x = src[(size_t)r * HD + lane];
  float ss = x * x;
#pragma unroll
  for (int m = 16; m >= 1; m >>= 1) ss += __shfl_xor(ss, m);
  float y = x / fmaxf(sqrtf(ss), 1e-12f);
  if (isQ) {
    const int h = (r >> 10) & (HEADS - 1);
    float scale = log1pf(__expf(temperature[h])) * sls[0];
    y = (y + qe[h * HD + lane]) * scale;
    float s2 = y * y;
#pragma unroll
    for (int m = 16; m >= 1; m >>= 1) s2 += __shfl_xor(s2, m);
    if (lane == 0) qmag[r] = sqrtf(s2);
  }
  unsigned short hi = f2bf(y);
  unsigned short lo = f2bf(y - bf2f(hi));
  if (isQ) {
    size_t idx = (size_t)r * HD + lane;
    qh[idx] = hi; ql[idx] = lo;
  } else {
    const int bh = r >> 10, n = r & 1023;
    const int kt = n >> 5, kr = n & 31;
    const int s = (kr >> 2) & 1;
    const int l16v = 4 * (kr >> 3) + (kr & 3);
    size_t idx = ((((size_t)bh * 32 + kt) * 2 + s) * 512)
                 + (l16v + 16 * (lane >> 3)) * 8 + (lane & 7);
    khT[idx] = hi; klT[idx] = lo;
  }
}

// ---------------------------------------------------------------------------
// V transpose into TILED fragment layout: element V[n][d] ->
// vtT[((bh*32 + n>>5)*2 + d>>4)*512 + ((d&15) + 16*((n>>3)&3))*8 + (n&7)].
// Attn vt-loads become 1KB contiguous per wave.
// ---------------------------------------------------------------------------
__global__ __launch_bounds__(256) void vt_kernel(
    const float* __restrict__ vb, unsigned short* __restrict__ vtT)
{
  __shared__ float tile[32][257];
  const int bh = blockIdx.x, ch = blockIdx.y;
  const int t = threadIdx.x;
  const float* src = vb + ((size_t)bh * NSEQ + ch * 256) * HD;
#pragma unroll
  for (int i = 0; i < 32; ++i) {
    int idx = i * 256 + t;                 // coalesced read; tile[d][n_local]
    tile[idx & 31][idx >> 5] = src[idx];
  }
  __syncthreads();
  unsigned short* dst = vtT + (size_t)bh * 32 * 2 * 512;
#pragma unroll
  for (int i = 0; i < 32; ++i) {
    int idx = i * 256 + t;
    int d = idx >> 8, nl = idx & 255;
    int n = ch * 256 + nl;
    size_t a = (((size_t)(n >> 5) * 2) + (d >> 4)) * 512
               + ((d & 15) + 16 * ((n >> 3) & 3)) * 8 + (n & 7);
    dst[a] = f2bf(tile[d][nl]);
  }
}

// ---------------------------------------------------------------------------
// MFMA flash attention, static-bound softmax (validated math, byte-identical
// per-lane values). STRUCTURAL CHANGE vs r6-r9: 16 queries/wave (one group)
// -> 8192 waves (2x TLP), and all fragment streams in tiled layouts so every
// wave-load is 1KB fully contiguous (8x128B transactions, was 16x64B).
// No manual prefetch (proven no-op r8/r9); latency hidden by occupancy.
// ---------------------------------------------------------------------------
__global__ __launch_bounds__(256, 6) void attn_mfma_kernel(
    const unsigned short* __restrict__ qh, const unsigned short* __restrict__ ql,
    const unsigned short* __restrict__ khT, const unsigned short* __restrict__ klT,
    const unsigned short* __restrict__ vtT, const unsigned short* __restrict__ rbT,
    const float* __restrict__ qmag, const float* __restrict__ rbmax,
    unsigned short* __restrict__ aoh, unsigned short* __restrict__ aol)
{
  const int bh = blockIdx.x;
  const int h = bh & (HEADS - 1), b = bh >> 4;
  const int wave = threadIdx.x >> 6;
  const int lane = threadIdx.x & 63;
  const int l16 = lane & 15, hi4 = lane >> 4;
  const int qbase = blockIdx.y * 64 + wave * 16;

  const int qrow = qbase + l16;
  bf16x8 qhf, qlf;
  {
    size_t ro = ((size_t)bh * NSEQ + qrow) * HD + hi4 * 8;
    qhf = *(const bf16x8*)(qh + ro);
    qlf = *(const bf16x8*)(ql + ro);
  }
  const float Ms = qmag[(size_t)bh * NSEQ + qrow] * (1.01f * LOG2E)
                   + rbmax[h * NSEQ + qrow] + 0.2f;

  bf16x8 ones;
#pragma unroll
  for (int j = 0; j < 8; ++j) ones[j] = (short)0x3f80;

  f32x4 accV0 = {}, accV1 = {}, accL = {};

  const unsigned short* khB = khT + (size_t)bh * 32768 + lane * 8;
  const unsigned short* klB = klT + (size_t)bh * 32768 + lane * 8;
  const unsigned short* vtB = vtT + (size_t)bh * 32768 + lane * 8;
  const unsigned short* rbB = rbT
      + ((size_t)(h * 64 + blockIdx.y * 4 + wave) * 32) * 512 + lane * 8;

  for (int kt = 0; kt < 32; ++kt) {
    bf16x8 kh0 = *(const bf16x8*)(khB + kt * 1024);
    bf16x8 kh1 = *(const bf16x8*)(khB + kt * 1024 + 512);
    bf16x8 kl0 = *(const bf16x8*)(klB + kt * 1024);
    bf16x8 kl1 = *(const bf16x8*)(klB + kt * 1024 + 512);
    bf16x8 vt0 = *(const bf16x8*)(vtB + kt * 1024);
    bf16x8 vt1 = *(const bf16x8*)(vtB + kt * 1024 + 512);
    bf16x8 b8  = *(const bf16x8*)(rbB + kt * 512);

    f32x4 D0 = {0.f, 0.f, 0.f, 0.f};
    f32x4 D1 = {0.f, 0.f, 0.f, 0.f};
    __builtin_amdgcn_s_setprio(1);
    D0 = __builtin_amdgcn_mfma_f32_16x16x32_bf16(kh0, qhf, D0, 0, 0, 0);
    D0 = __builtin_amdgcn_mfma_f32_16x16x32_bf16(kh0, qlf, D0, 0, 0, 0);
    D0 = __builtin_amdgcn_mfma_f32_16x16x32_bf16(kl0, qhf, D0, 0, 0, 0);
    D1 = __builtin_amdgcn_mfma_f32_16x16x32_bf16(kh1, qhf, D1, 0, 0, 0);
    D1 = __builtin_amdgcn_mfma_f32_16x16x32_bf16(kh1, qlf, D1, 0, 0, 0);
    D1 = __builtin_amdgcn_mfma_f32_16x16x32_bf16(kl1, qhf, D1, 0, 0, 0);
    __builtin_amdgcn_s_setprio(0);

    float p0[4], p1[4];
#pragma unroll
    for (int r = 0; r < 4; ++r) {
      float a0 = fmaf(D0[r], LOG2E, bf2f((unsigned short)b8[r]))     - Ms;
      float a1 = fmaf(D1[r], LOG2E, bf2f((unsigned short)b8[4 + r])) - Ms;
      p0[r] = __builtin_amdgcn_exp2f(a0);
      p1[r] = __builtin_amdgcn_exp2f(a1);
    }
    union { bf16x8 v; unsigned u[4]; } pa;
    pa.u[0] = cvt_pk_bf16(p0[0], p0[1]);
    pa.u[1] = cvt_pk_bf16(p0[2], p0[3]);
    pa.u[2] = cvt_pk_bf16(p1[0], p1[1]);
    pa.u[3] = cvt_pk_bf16(p1[2], p1[3]);

    __builtin_amdgcn_s_setprio(1);
    accV0 = __builtin_amdgcn_mfma_f32_16x16x32_bf16(pa.v, vt0, accV0, 0, 0, 0);
    accV1 = __builtin_amdgcn_mfma_f32_16x16x32_bf16(pa.v, vt1, accV1, 0, 0, 0);
    accL  = __builtin_amdgcn_mfma_f32_16x16x32_bf16(pa.v, ones, accL, 0, 0, 0);
    __builtin_amdgcn_s_setprio(0);
  }

#pragma unroll
  for (int r = 0; r < 4; ++r) {
    float inv = 1.f / accL[r];
#pragma unroll
    for (int df = 0; df < 2; ++df) {
      size_t idx = ((size_t)b * NSEQ + qbase + hi4 * 4 + r) * DIMC
                   + h * HD + df * 16 + l16;
      float val = (df ? accV1[r] : accV0[r]) * inv;
      unsigned short hh = f2bf(val);
      aoh[idx] = hh;
      aol[idx] = f2bf(val - bf2f(hh));
    }
  }
}

// ---------------------------------------------------------------------------
extern "C" void kernel_launch(void* const* d_in, const int* in_sizes, int n_in,
                              void* d_out, int out_size, void* d_ws, size_t ws_size,
                              hipStream_t stream)
{
  (void)in_sizes; (void)n_in; (void)out_size; (void)ws_size;
  const float* x      = (const float*)d_in[0];
  const float* qkv_w  = (const float*)d_in[1];
  const float* qkv_b  = (const float*)d_in[2];
  const float* proj_w = (const float*)d_in[3];
  const float* proj_b = (const float*)d_in[4];
  const float* temp   = (const float*)d_in[5];
  const float* qe     = (const float*)d_in[6];
  const float* fc1w   = (const float*)d_in[7];
  const float* fc1b   = (const float*)d_in[8];
  const float* fc2w   = (const float*)d_in[9];
  const float* fc2b   = (const float*)d_in[10];
  const float* tbl    = (const float*)d_in[11];
  const int*   rpi    = (const int*)d_in[12];
  const float* sls    = (const float*)d_in[13];
  // H=W=32 == trained resolution: both bilinear resizes are identity;
  // bias[h,n,m] = t[rpi[n*1024+m], h].

  char* ws = (char*)d_ws;
  const size_t perT = (size_t)BATCH * HEADS * NSEQ * HD;    // 4,194,304
  float* qb = (float*)ws;
  float* kb = qb + perT;
  float* vb = kb + perT;
  float* tT = vb + perT;                                    // 65536 f32 slot
  unsigned short* qh = (unsigned short*)(tT + 65536);
  unsigned short* ql = qh + perT;
  unsigned short* khT = ql + perT;
  unsigned short* klT = khT + perT;
  unsigned short* vtT = klT + perT;
  unsigned short* xh = vtT + perT;
  unsigned short* xl = xh + perT;
  unsigned short* pwh = xl + perT;                          // 262144
  unsigned short* pwl = pwh + 262144;
  float* rbmax = (float*)(pwl + 262144);                    // 16384 f32
  float* qmag  = rbmax + 16384;                             // QROWS f32
  // aliases (stream-ordered lifetimes):
  unsigned short* qwh = qh;              // dead before normsplit writes qh
  unsigned short* qwl = qh + 786432;
  unsigned short* rbT = (unsigned short*)qb;  // qb/kb dead after normsplit
  unsigned short* aoh = xh;              // xh/xl dead after gemm_qkv
  unsigned short* aol = xl;

  split_kernel<<<dim3(4096), 256, 0, stream>>>(x, xh, xl, 1048576);
  split_kernel<<<dim3(768),  256, 0, stream>>>(qkv_w, qwh, qwl, 196608);
  split_kernel<<<dim3(256),  256, 0, stream>>>(proj_w, pwh, pwl, 65536);
  gemm_split_kernel<0><<<dim3(12, 64), 256, 0, stream>>>(
      xh, xl, qwh, qwl, qkv_b, qb, kb, vb);
  cpb_kernel<<<dim3(TBLN), 256, 0, stream>>>(tbl, fc1w, fc1b, fc2w, fc2b, tT);
  normsplit_kernel<<<dim3((2*QROWS*32)/256), 256, 0, stream>>>(
      qb, kb, temp, qe, sls, qh, ql, khT, klT, qmag);
  vt_kernel<<<dim3(BATCH*HEADS, NSEQ/256), 256, 0, stream>>>(vb, vtT);
  rb_gather_kernel<<<dim3((NSEQ*NSEQ/8)/256), 256, 0, stream>>>(tT, rpi, rbT);
  rowmax_kernel<<<dim3(HEADS*NSEQ/4), 256, 0, stream>>>(rbT, rbmax);
  attn_mfma_kernel<<<dim3(BATCH*HEADS, NSEQ/64), 256, 0, stream>>>(
      qh, ql, khT, klT, vtT, rbT, qmag, rbmax, aoh, aol);
  gemm_split_kernel<1><<<dim3(4, 64), 256, 0, stream>>>(
      aoh, aol, pwh, pwl, proj_b, (float*)d_out, nullptr, nullptr);
}

// Round 11
// 339.847 us; speedup vs baseline: 1.1445x; 1.0407x over previous
//
#include <hip/hip_runtime.h>
#include <math.h>

#define BATCH 8
#define NSEQ  1024
#define DIMC  512
#define HEADS 16
#define HD    32
#define TBLN  3969
#define QROWS (BATCH*HEADS*NSEQ)
#define LOG2E 1.4426950408889634f

typedef __attribute__((ext_vector_type(8))) short bf16x8;
typedef __attribute__((ext_vector_type(4))) float f32x4;

__device__ __forceinline__ unsigned short f2bf(float f) {
  union { float f; unsigned u; } c; c.f = f;
  unsigned x = c.u + 0x7fffu + ((c.u >> 16) & 1u);   // RNE
  return (unsigned short)(x >> 16);
}
__device__ __forceinline__ float bf2f(unsigned short h) {
  union { unsigned u; float f; } c; c.u = ((unsigned)h) << 16; return c.f;
}
__device__ __forceinline__ unsigned cvt_pk_bf16(float lo, float hi) {
  unsigned r;
  asm("v_cvt_pk_bf16_f32 %0, %1, %2" : "=v"(r) : "v"(lo), "v"(hi));
  return r;
}

#define GLD(gsrc, ldst) __builtin_amdgcn_global_load_lds( \
      (const __attribute__((address_space(1))) unsigned int*)(gsrc), \
      (__attribute__((address_space(3))) unsigned int*)(ldst), 16, 0, 0)

// ---------------------------------------------------------------------------
// hi/lo bf16 split of an fp32 array (float4 per thread).
// ---------------------------------------------------------------------------
__global__ __launch_bounds__(256) void split_kernel(
    const float* __restrict__ src, unsigned short* __restrict__ hi,
    unsigned short* __restrict__ lo, int n4)
{
  int gid = blockIdx.x * 256 + threadIdx.x;
  if (gid >= n4) return;
  float4 v = ((const float4*)src)[gid];
  float vv[4] = {v.x, v.y, v.z, v.w};
  unsigned short h[4], l[4];
#pragma unroll
  for (int i = 0; i < 4; ++i) {
    h[i] = f2bf(vv[i]);
    l[i] = f2bf(vv[i] - bf2f(h[i]));
  }
  uint2 hp, lp;
  hp.x = h[0] | ((unsigned)h[1] << 16); hp.y = h[2] | ((unsigned)h[3] << 16);
  lp.x = l[0] | ((unsigned)l[1] << 16); lp.y = l[2] | ((unsigned)l[3] << 16);
  ((uint2*)hi)[gid] = hp;
  ((uint2*)lo)[gid] = lp;
}

// ---------------------------------------------------------------------------
// Split-bf16 MFMA GEMM, templated on tile rows BM (128 or 64).
// BM=128: grid(x=N/128, y=M/128), 32KB LDS (qkv).  BM=64: grid(x=N/128,
// y=M/64), 24KB LDS, 2 blocks/CU for the proj GEMM (was 1 -> barrier-bound).
// EPI 0: q,k -> f32 [B][H][N][HD]; v -> bf16 DIRECTLY in tiled vtT layout
// (vt_kernel eliminated; formula verified against attn's read map).
// EPI 1: plain f32 [M][512] write.
// ---------------------------------------------------------------------------
template<int EPI, int BM>
__global__ __launch_bounds__(256) void gemm_split_kernel(
    const unsigned short* __restrict__ Ah, const unsigned short* __restrict__ Al,
    const unsigned short* __restrict__ Wh, const unsigned short* __restrict__ Wl,
    const float* __restrict__ bias,
    float* __restrict__ o0p, float* __restrict__ o1p,
    unsigned short* __restrict__ vtp)
{
  const int K = DIMC;
  constexpr int ASZ = BM * 32;            // shorts per A tile
  constexpr int FI  = BM / 32;            // 16-row fragments per wave
  __shared__ __align__(16) unsigned short lds[2 * ASZ + 8192];
  unsigned short* ldsAh = lds;
  unsigned short* ldsAl = lds + ASZ;
  unsigned short* ldsBh = lds + 2 * ASZ;
  unsigned short* ldsBl = lds + 2 * ASZ + 4096;
  const int tid = threadIdx.x;
  const int wave = tid >> 6, lane = tid & 63;
  const int l16 = lane & 15, hi4 = lane >> 4;
  const int rowBase = blockIdx.y * BM, colBase = blockIdx.x * 128;
  const int warpRow = (wave >> 1) * (BM / 2), warpCol = (wave & 1) * 64;

  // staging geometry (inverse-swizzled global source, linear LDS dest)
  const int oB0 = wave * 2048 + lane * 16;
  const int oB1 = oB0 + 1024;
  const int rB0 = oB0 >> 6, sB0 = (oB0 >> 4) & 3;
  const int rB1 = oB1 >> 6, sB1 = (oB1 >> 4) & 3;
  const int gB0 = rB0 * K + ((sB0 ^ ((rB0 >> 1) & 3)) << 3);
  const int gB1 = rB1 * K + ((sB1 ^ ((rB1 >> 1) & 3)) << 3);
  const int oA0 = (BM == 128) ? (wave * 2048 + lane * 16)
                              : (wave * 1024 + lane * 16);
  const int oA1 = oA0 + 1024;             // used only when BM==128
  const int rA0 = oA0 >> 6, sA0 = (oA0 >> 4) & 3;
  const int rA1 = oA1 >> 6, sA1 = (oA1 >> 4) & 3;
  const int gA0 = rA0 * K + ((sA0 ^ ((rA0 >> 1) & 3)) << 3);
  const int gA1 = rA1 * K + ((sA1 ^ ((rA1 >> 1) & 3)) << 3);

  const unsigned short* A0h = Ah + (size_t)rowBase * K;
  const unsigned short* A0l = Al + (size_t)rowBase * K;
  const unsigned short* W0h = Wh + (size_t)colBase * K;
  const unsigned short* W0l = Wl + (size_t)colBase * K;

  f32x4 acc[FI][4] = {};

  float biasv[4];
#pragma unroll
  for (int fj = 0; fj < 4; ++fj)
    biasv[fj] = bias[colBase + warpCol + fj * 16 + l16];

  int ra[FI], rbq[4];
#pragma unroll
  for (int f = 0; f < FI; ++f) {
    int rowA = warpRow + f * 16 + l16;
    ra[f] = rowA * 64 + ((hi4 ^ ((rowA >> 1) & 3)) << 4);
  }
#pragma unroll
  for (int f = 0; f < 4; ++f) {
    int rowB = warpCol + f * 16 + l16;
    rbq[f] = rowB * 64 + ((hi4 ^ ((rowB >> 1) & 3)) << 4);
  }

  for (int k0 = 0; k0 < K; k0 += 32) {
    __syncthreads();
    GLD(A0h + k0 + gA0, (char*)ldsAh + oA0);
    GLD(A0l + k0 + gA0, (char*)ldsAl + oA0);
    if constexpr (BM == 128) {
      GLD(A0h + k0 + gA1, (char*)ldsAh + oA1);
      GLD(A0l + k0 + gA1, (char*)ldsAl + oA1);
    }
    GLD(W0h + k0 + gB0, (char*)ldsBh + oB0);
    GLD(W0h + k0 + gB1, (char*)ldsBh + oB1);
    GLD(W0l + k0 + gB0, (char*)ldsBl + oB0);
    GLD(W0l + k0 + gB1, (char*)ldsBl + oB1);
    __syncthreads();

    bf16x8 a_h[FI], a_l[FI], b_h[4], b_l[4];
#pragma unroll
    for (int f = 0; f < FI; ++f) {
      a_h[f] = *(const bf16x8*)((const char*)ldsAh + ra[f]);
      a_l[f] = *(const bf16x8*)((const char*)ldsAl + ra[f]);
    }
#pragma unroll
    for (int f = 0; f < 4; ++f) {
      b_h[f] = *(const bf16x8*)((const char*)ldsBh + rbq[f]);
      b_l[f] = *(const bf16x8*)((const char*)ldsBl + rbq[f]);
    }
#pragma unroll
    for (int fi = 0; fi < FI; ++fi)
#pragma unroll
      for (int fj = 0; fj < 4; ++fj) {
        acc[fi][fj] = __builtin_amdgcn_mfma_f32_16x16x32_bf16(a_l[fi], b_h[fj], acc[fi][fj], 0, 0, 0);
        acc[fi][fj] = __builtin_amdgcn_mfma_f32_16x16x32_bf16(a_h[fi], b_l[fj], acc[fi][fj], 0, 0, 0);
        acc[fi][fj] = __builtin_amdgcn_mfma_f32_16x16x32_bf16(a_h[fi], b_h[fj], acc[fi][fj], 0, 0, 0);
      }
  }

#pragma unroll
  for (int fi = 0; fi < FI; ++fi)
#pragma unroll
    for (int fj = 0; fj < 4; ++fj)
#pragma unroll
      for (int r = 0; r < 4; ++r) {
        int m = rowBase + warpRow + fi * 16 + hi4 * 4 + r;
        int c = colBase + warpCol + fj * 16 + l16;
        float val = acc[fi][fj][r] + biasv[fj];
        if (EPI == 0) {
          int b = m >> 10, n = m & 1023;
          int which = c >> 9, rem = c & 511;
          int hh = rem >> 5, d = rem & 31;
          if (which == 2) {
            // v -> bf16 tiled vtT (verified vs attn read map)
            int bh = b * HEADS + hh;
            size_t a = (size_t)bh * 32768
                     + (size_t)(n >> 5) * 1024 + (size_t)(d >> 4) * 512
                     + ((d & 15) + 16 * ((n >> 3) & 3)) * 8 + (n & 7);
            vtp[a] = f2bf(val);
          } else {
            float* dst = (which == 0) ? o0p : o1p;
            dst[(((size_t)b * HEADS + hh) * NSEQ + n) * HD + d] = val;
          }
        } else {
          o0p[(size_t)m * DIMC + c] = val;
        }
      }
}

// ---------------------------------------------------------------------------
// CPB MLP (unchanged) -> tT [16][TBLN] f32
// ---------------------------------------------------------------------------
__global__ __launch_bounds__(256) void cpb_kernel(
    const float* __restrict__ table, const float* __restrict__ fc1w,
    const float* __restrict__ fc1b, const float* __restrict__ fc2w,
    const float* __restrict__ fc2b, float* __restrict__ tT)
{
  const int row = blockIdx.x;
  const float c0 = table[row*2], c1 = table[row*2+1];
  __shared__ float hid[512];
  __shared__ float red[256];
  const int tid = threadIdx.x;
  for (int j = tid; j < 512; j += 256)
    hid[j] = fmaxf(fmaf(c0, fc1w[j*2], fmaf(c1, fc1w[j*2+1], fc1b[j])), 0.f);
  __syncthreads();
  const int h = tid & 15, part = tid >> 4;
  float s = 0.f;
#pragma unroll
  for (int jj = 0; jj < 32; ++jj) {
    int j = part*32 + jj;
    s = fmaf(hid[j], fc2w[h*512 + j], s);
  }
  red[tid] = s;
  __syncthreads();
  if (tid < 16) {
    float t = fc2b[tid];
#pragma unroll
    for (int p = 0; p < 16; ++p) t += red[tid + p*16];
    tT[(size_t)tid * TBLN + row] = t;
  }
}

// ---------------------------------------------------------------------------
// rb materialization into TILED fragment layout (unchanged from r10).
// ---------------------------------------------------------------------------
__global__ __launch_bounds__(256) void rb_gather_kernel(
    const float* __restrict__ tT, const int* __restrict__ rpi,
    unsigned short* __restrict__ rbT)
{
  int gid = blockIdx.x * 256 + threadIdx.x;   // over N*(N/8)
  int n = gid >> 7, m8 = gid & 127;
  int idx[8];
#pragma unroll
  for (int j = 0; j < 8; ++j) idx[j] = rpi[(size_t)n * NSEQ + m8 * 8 + j];
  const int kt = m8 >> 2, hi4v = m8 & 3;
  const size_t base = (((size_t)0 * 64 + (n >> 4)) * 32 + kt) * 512
                      + ((n & 15) + 16 * hi4v) * 8;
#pragma unroll
  for (int h = 0; h < 16; ++h) {
    bf16x8 v;
#pragma unroll
    for (int j = 0; j < 8; ++j)
      v[j] = (short)f2bf(tT[h * TBLN + idx[j]] * LOG2E);
    *(bf16x8*)(rbT + base + (size_t)h * 64 * 32 * 512) = v;
  }
}

// ---------------------------------------------------------------------------
// Per-(h,q) row max over tiled rbT (unchanged from r10).
// ---------------------------------------------------------------------------
__global__ __launch_bounds__(256) void rowmax_kernel(
    const unsigned short* __restrict__ rbT, float* __restrict__ rbmax)
{
  const int row = blockIdx.x * 4 + (threadIdx.x >> 6);
  const int lane = threadIdx.x & 63;
  const int h = row >> 10, n = row & 1023;
  const int kt = lane >> 1, half = lane & 1;
  const size_t base = (((size_t)h * 64 + (n >> 4)) * 32 + kt) * 512;
  bf16x8 a = *(const bf16x8*)(rbT + base + ((n & 15) + 16 * (2 * half)) * 8);
  bf16x8 b = *(const bf16x8*)(rbT + base + ((n & 15) + 16 * (2 * half + 1)) * 8);
  float m = -1e30f;
#pragma unroll
  for (int j = 0; j < 8; ++j) {
    m = fmaxf(m, bf2f((unsigned short)a[j]));
    m = fmaxf(m, bf2f((unsigned short)b[j]));
  }
#pragma unroll
  for (int s = 32; s >= 1; s >>= 1) m = fmaxf(m, __shfl_xor(m, s));
  if (lane == 0) rbmax[row] = m;
}

// ---------------------------------------------------------------------------
// Normalize q,k, emit hi/lo bf16 splits + qmag (unchanged from r10).
// K written in tiled fragment layout.
// ---------------------------------------------------------------------------
__global__ __launch_bounds__(256) void normsplit_kernel(
    const float* __restrict__ qb, const float* __restrict__ kb,
    const float* __restrict__ temperature, const float* __restrict__ qe,
    const float* __restrict__ sls,
    unsigned short* __restrict__ qh, unsigned short* __restrict__ ql,
    unsigned short* __restrict__ khT, unsigned short* __restrict__ klT,
    float* __restrict__ qmag)
{
  const int gid = blockIdx.x * 256 + threadIdx.x;
  const int lane = gid & 31;             // d
  const int row = gid >> 5;
  const bool isQ = row < QROWS;
  const float* src = isQ ? qb : kb;
  const int r = isQ ? row : row - QROWS;
  float x = src[(size_t)r * HD + lane];
  float ss = x * x;
#pragma unroll
  for (int m = 16; m >= 1; m >>= 1) ss += __shfl_xor(ss, m);
  float y = x / fmaxf(sqrtf(ss), 1e-12f);
  if (isQ) {
    const int h = (r >> 10) & (HEADS - 1);
    float scale = log1pf(__expf(temperature[h])) * sls[0];
    y = (y + qe[h * HD + lane]) * scale;
    float s2 = y * y;
#pragma unroll
    for (int m = 16; m >= 1; m >>= 1) s2 += __shfl_xor(s2, m);
    if (lane == 0) qmag[r] = sqrtf(s2);
  }
  unsigned short hi = f2bf(y);
  unsigned short lo = f2bf(y - bf2f(hi));
  if (isQ) {
    size_t idx = (size_t)r * HD + lane;
    qh[idx] = hi; ql[idx] = lo;
  } else {
    const int bh = r >> 10, n = r & 1023;
    const int kt = n >> 5, kr = n & 31;
    const int s = (kr >> 2) & 1;
    const int l16v = 4 * (kr >> 3) + (kr & 3);
    size_t idx = ((((size_t)bh * 32 + kt) * 2 + s) * 512)
                 + (l16v + 16 * (lane >> 3)) * 8 + (lane & 7);
    khT[idx] = hi; klT[idx] = lo;
  }
}

// ---------------------------------------------------------------------------
// MFMA flash attention (unchanged from r10 — validated, 83 us).
// ---------------------------------------------------------------------------
__global__ __launch_bounds__(256, 6) void attn_mfma_kernel(
    const unsigned short* __restrict__ qh, const unsigned short* __restrict__ ql,
    const unsigned short* __restrict__ khT, const unsigned short* __restrict__ klT,
    const unsigned short* __restrict__ vtT, const unsigned short* __restrict__ rbT,
    const float* __restrict__ qmag, const float* __restrict__ rbmax,
    unsigned short* __restrict__ aoh, unsigned short* __restrict__ aol)
{
  const int bh = blockIdx.x;
  const int h = bh & (HEADS - 1), b = bh >> 4;
  const int wave = threadIdx.x >> 6;
  const int lane = threadIdx.x & 63;
  const int l16 = lane & 15, hi4 = lane >> 4;
  const int qbase = blockIdx.y * 64 + wave * 16;

  const int qrow = qbase + l16;
  bf16x8 qhf, qlf;
  {
    size_t ro = ((size_t)bh * NSEQ + qrow) * HD + hi4 * 8;
    qhf = *(const bf16x8*)(qh + ro);
    qlf = *(const bf16x8*)(ql + ro);
  }
  const float Ms = qmag[(size_t)bh * NSEQ + qrow] * (1.01f * LOG2E)
                   + rbmax[h * NSEQ + qrow] + 0.2f;

  bf16x8 ones;
#pragma unroll
  for (int j = 0; j < 8; ++j) ones[j] = (short)0x3f80;

  f32x4 accV0 = {}, accV1 = {}, accL = {};

  const unsigned short* khB = khT + (size_t)bh * 32768 + lane * 8;
  const unsigned short* klB = klT + (size_t)bh * 32768 + lane * 8;
  const unsigned short* vtB = vtT + (size_t)bh * 32768 + lane * 8;
  const unsigned short* rbB = rbT
      + ((size_t)(h * 64 + blockIdx.y * 4 + wave) * 32) * 512 + lane * 8;

  for (int kt = 0; kt < 32; ++kt) {
    bf16x8 kh0 = *(const bf16x8*)(khB + kt * 1024);
    bf16x8 kh1 = *(const bf16x8*)(khB + kt * 1024 + 512);
    bf16x8 kl0 = *(const bf16x8*)(klB + kt * 1024);
    bf16x8 kl1 = *(const bf16x8*)(klB + kt * 1024 + 512);
    bf16x8 vt0 = *(const bf16x8*)(vtB + kt * 1024);
    bf16x8 vt1 = *(const bf16x8*)(vtB + kt * 1024 + 512);
    bf16x8 b8  = *(const bf16x8*)(rbB + kt * 512);

    f32x4 D0 = {0.f, 0.f, 0.f, 0.f};
    f32x4 D1 = {0.f, 0.f, 0.f, 0.f};
    __builtin_amdgcn_s_setprio(1);
    D0 = __builtin_amdgcn_mfma_f32_16x16x32_bf16(kh0, qhf, D0, 0, 0, 0);
    D0 = __builtin_amdgcn_mfma_f32_16x16x32_bf16(kh0, qlf, D0, 0, 0, 0);
    D0 = __builtin_amdgcn_mfma_f32_16x16x32_bf16(kl0, qhf, D0, 0, 0, 0);
    D1 = __builtin_amdgcn_mfma_f32_16x16x32_bf16(kh1, qhf, D1, 0, 0, 0);
    D1 = __builtin_amdgcn_mfma_f32_16x16x32_bf16(kh1, qlf, D1, 0, 0, 0);
    D1 = __builtin_amdgcn_mfma_f32_16x16x32_bf16(kl1, qhf, D1, 0, 0, 0);
    __builtin_amdgcn_s_setprio(0);

    float p0[4], p1[4];
#pragma unroll
    for (int r = 0; r < 4; ++r) {
      float a0 = fmaf(D0[r], LOG2E, bf2f((unsigned short)b8[r]))     - Ms;
      float a1 = fmaf(D1[r], LOG2E, bf2f((unsigned short)b8[4 + r])) - Ms;
      p0[r] = __builtin_amdgcn_exp2f(a0);
      p1[r] = __builtin_amdgcn_exp2f(a1);
    }
    union { bf16x8 v; unsigned u[4]; } pa;
    pa.u[0] = cvt_pk_bf16(p0[0], p0[1]);
    pa.u[1] = cvt_pk_bf16(p0[2], p0[3]);
    pa.u[2] = cvt_pk_bf16(p1[0], p1[1]);
    pa.u[3] = cvt_pk_bf16(p1[2], p1[3]);

    __builtin_amdgcn_s_setprio(1);
    accV0 = __builtin_amdgcn_mfma_f32_16x16x32_bf16(pa.v, vt0, accV0, 0, 0, 0);
    accV1 = __builtin_amdgcn_mfma_f32_16x16x32_bf16(pa.v, vt1, accV1, 0, 0, 0);
    accL  = __builtin_amdgcn_mfma_f32_16x16x32_bf16(pa.v, ones, accL, 0, 0, 0);
    __builtin_amdgcn_s_setprio(0);
  }

#pragma unroll
  for (int r = 0; r < 4; ++r) {
    float inv = 1.f / accL[r];
#pragma unroll
    for (int df = 0; df < 2; ++df) {
      size_t idx = ((size_t)b * NSEQ + qbase + hi4 * 4 + r) * DIMC
                   + h * HD + df * 16 + l16;
      float val = (df ? accV1[r] : accV0[r]) * inv;
      unsigned short hh = f2bf(val);
      aoh[idx] = hh;
      aol[idx] = f2bf(val - bf2f(hh));
    }
  }
}

// ---------------------------------------------------------------------------
extern "C" void kernel_launch(void* const* d_in, const int* in_sizes, int n_in,
                              void* d_out, int out_size, void* d_ws, size_t ws_size,
                              hipStream_t stream)
{
  (void)in_sizes; (void)n_in; (void)out_size; (void)ws_size;
  const float* x      = (const float*)d_in[0];
  const float* qkv_w  = (const float*)d_in[1];
  const float* qkv_b  = (const float*)d_in[2];
  const float* proj_w = (const float*)d_in[3];
  const float* proj_b = (const float*)d_in[4];
  const float* temp   = (const float*)d_in[5];
  const float* qe     = (const float*)d_in[6];
  const float* fc1w   = (const float*)d_in[7];
  const float* fc1b   = (const float*)d_in[8];
  const float* fc2w   = (const float*)d_in[9];
  const float* fc2b   = (const float*)d_in[10];
  const float* tbl    = (const float*)d_in[11];
  const int*   rpi    = (const int*)d_in[12];
  const float* sls    = (const float*)d_in[13];
  // H=W=32 == trained resolution: both bilinear resizes are identity;
  // bias[h,n,m] = t[rpi[n*1024+m], h].

  char* ws = (char*)d_ws;
  const size_t perT = (size_t)BATCH * HEADS * NSEQ * HD;    // 4,194,304
  float* qb = (float*)ws;
  float* kb = qb + perT;
  float* vb = kb + perT;                                    // (slot unused now)
  float* tT = vb + perT;                                    // 65536 f32 slot
  unsigned short* qh = (unsigned short*)(tT + 65536);
  unsigned short* ql = qh + perT;
  unsigned short* khT = ql + perT;
  unsigned short* klT = khT + perT;
  unsigned short* vtT = klT + perT;
  unsigned short* xh = vtT + perT;
  unsigned short* xl = xh + perT;
  unsigned short* pwh = xl + perT;                          // 262144
  unsigned short* pwl = pwh + 262144;
  float* rbmax = (float*)(pwl + 262144);                    // 16384 f32
  float* qmag  = rbmax + 16384;                             // QROWS f32
  // aliases (stream-ordered lifetimes):
  unsigned short* qwh = qh;              // dead before normsplit writes qh
  unsigned short* qwl = qh + 786432;
  unsigned short* rbT = (unsigned short*)qb;  // qb/kb dead after normsplit
  unsigned short* aoh = xh;              // xh/xl dead after gemm_qkv
  unsigned short* aol = xl;

  split_kernel<<<dim3(4096), 256, 0, stream>>>(x, xh, xl, 1048576);
  split_kernel<<<dim3(768),  256, 0, stream>>>(qkv_w, qwh, qwl, 196608);
  split_kernel<<<dim3(256),  256, 0, stream>>>(proj_w, pwh, pwl, 65536);
  gemm_split_kernel<0, 128><<<dim3(12, 64), 256, 0, stream>>>(
      xh, xl, qwh, qwl, qkv_b, qb, kb, vtT);
  cpb_kernel<<<dim3(TBLN), 256, 0, stream>>>(tbl, fc1w, fc1b, fc2w, fc2b, tT);
  normsplit_kernel<<<dim3((2*QROWS*32)/256), 256, 0, stream>>>(
      qb, kb, temp, qe, sls, qh, ql, khT, klT, qmag);
  rb_gather_kernel<<<dim3((NSEQ*NSEQ/8)/256), 256, 0, stream>>>(tT, rpi, rbT);
  rowmax_kernel<<<dim3(HEADS*NSEQ/4), 256, 0, stream>>>(rbT, rbmax);
  attn_mfma_kernel<<<dim3(BATCH*HEADS, NSEQ/64), 256, 0, stream>>>(
      qh, ql, khT, klT, vtT, rbT, qmag, rbmax, aoh, aol);
  gemm_split_kernel<1, 64><<<dim3(4, 128), 256, 0, stream>>>(
      aoh, aol, pwh, pwl, proj_b, (float*)d_out, nullptr, nullptr);
}